// Round 1
// baseline (180.027 us; speedup 1.0000x reference)
//
#include <hip/hip_runtime.h>

// Problem constants: x shape (8, 19, 512, 1024) fp32
#define PH 512
#define PW 1024
#define NPLANES 152                   // 8*19
#define TOTAL_ELEMS (152ll * 512 * 1024)   // 79,691,776
#define TOTAL_VEC   (TOTAL_ELEMS / 4)      // 19,922,944
#define NBLOCKS 2048
#define NTHREADS 256

__global__ __launch_bounds__(NTHREADS) void box_loss_partial(
    const float* __restrict__ x, float* __restrict__ partial) {
    const long long stride = (long long)gridDim.x * blockDim.x;
    float acc = 0.f;
    for (long long idx = (long long)blockIdx.x * blockDim.x + threadIdx.x;
         idx < TOTAL_VEC; idx += stride) {
        // plane-vec layout: vecW = 256 (=PW/4), plane vec size = 512*256 = 2^17
        const int plane = (int)(idx >> 17);
        const int rem   = (int)(idx & ((1 << 17) - 1));
        const int h     = rem >> 8;        // 0..511
        const int wv    = rem & 255;       // vec index in row
        const int w     = wv << 2;         // 0..1020

        const float* base = x + ((long long)plane << 19);  // plane*512*1024

        float s0 = 0.f, s1 = 0.f, s2 = 0.f, s3 = 0.f;
        float4 c = make_float4(0.f, 0.f, 0.f, 0.f);

        #pragma unroll
        for (int dh = -1; dh <= 1; ++dh) {
            const int hr = h + dh;
            if (hr < 0 || hr >= PH) continue;   // zero padding row
            const float* row = base + ((long long)hr << 10) + w;
            const float4 f = *reinterpret_cast<const float4*>(row);
            const float l = (wv > 0)   ? row[-1] : 0.f;   // zero pad left
            const float r = (wv < 255) ? row[4]  : 0.f;   // zero pad right
            s0 += l   + f.x + f.y;
            s1 += f.x + f.y + f.z;
            s2 += f.y + f.z + f.w;
            s3 += f.z + f.w + r;
            if (dh == 0) c = f;
        }
        const float inv9 = 1.f / 9.f;
        acc += fabsf(c.x - s0 * inv9);
        acc += fabsf(c.y - s1 * inv9);
        acc += fabsf(c.z - s2 * inv9);
        acc += fabsf(c.w - s3 * inv9);
    }

    // wave (64-lane) tree reduction
    #pragma unroll
    for (int off = 32; off > 0; off >>= 1) acc += __shfl_down(acc, off, 64);

    __shared__ float smem[NTHREADS / 64];
    const int lane = threadIdx.x & 63;
    const int wid  = threadIdx.x >> 6;
    if (lane == 0) smem[wid] = acc;
    __syncthreads();
    if (threadIdx.x == 0) {
        float s = 0.f;
        #pragma unroll
        for (int i = 0; i < NTHREADS / 64; ++i) s += smem[i];
        partial[blockIdx.x] = s;
    }
}

__global__ __launch_bounds__(NTHREADS) void box_loss_final(
    const float* __restrict__ partial, float* __restrict__ out) {
    float acc = 0.f;
    for (int i = threadIdx.x; i < NBLOCKS; i += NTHREADS) acc += partial[i];
    #pragma unroll
    for (int off = 32; off > 0; off >>= 1) acc += __shfl_down(acc, off, 64);

    __shared__ float smem[NTHREADS / 64];
    const int lane = threadIdx.x & 63;
    const int wid  = threadIdx.x >> 6;
    if (lane == 0) smem[wid] = acc;
    __syncthreads();
    if (threadIdx.x == 0) {
        float s = 0.f;
        #pragma unroll
        for (int i = 0; i < NTHREADS / 64; ++i) s += smem[i];
        out[0] = s * (1.f / (float)TOTAL_ELEMS);
    }
}

extern "C" void kernel_launch(void* const* d_in, const int* in_sizes, int n_in,
                              void* d_out, int out_size, void* d_ws, size_t ws_size,
                              hipStream_t stream) {
    const float* x = (const float*)d_in[0];
    float* out = (float*)d_out;
    float* partial = (float*)d_ws;   // NBLOCKS floats = 8 KB

    box_loss_partial<<<NBLOCKS, NTHREADS, 0, stream>>>(x, partial);
    box_loss_final<<<1, NTHREADS, 0, stream>>>(partial, out);
}

// Round 2
// 75.168 us; speedup vs baseline: 2.3950x; 2.3950x over previous
//
#include <hip/hip_runtime.h>

// x shape (8, 19, 512, 1024) fp32
#define PH 512
#define PW 1024
#define NPLANES 152                        // 8*19
#define TOTAL_ELEMS (152ll * 512 * 1024)   // 79,691,776
#define RROWS 8                            // output rows per thread
#define NTILES (PH / RROWS)                // 64
#define NBLOCKS (NPLANES * NTILES)         // 9728
#define NTHREADS 256

__global__ __launch_bounds__(NTHREADS) void box_loss_partial(
    const float* __restrict__ x, float* __restrict__ partial) {
    const int wv    = threadIdx.x;         // 0..255, float4 column
    const int tile  = blockIdx.x & (NTILES - 1);
    const int plane = blockIdx.x / NTILES;
    const int h0    = tile * RROWS;

    const float* base = x + ((long long)plane << 19) + (wv << 2);

    // Load 10 rows (8 + 2 halo). Branchless: clamp row index, mask validity.
    float4 f[RROWS + 2];
    float  hl[RROWS + 2], hr[RROWS + 2], valid[RROWS + 2];
    #pragma unroll
    for (int i = 0; i < RROWS + 2; ++i) {
        const int hh = h0 - 1 + i;
        const int hc = min(max(hh, 0), PH - 1);
        const float* row = base + ((long long)hc << 10);
        f[i]  = *reinterpret_cast<const float4*>(row);
        hl[i] = (wv > 0)   ? row[-1] : 0.f;
        hr[i] = (wv < 255) ? row[4]  : 0.f;
        valid[i] = (hh >= 0 && hh < PH) ? 1.f : 0.f;
    }

    // Horizontal 3-sums per row (masked by validity for halo rows).
    float4 hs[RROWS + 2];
    #pragma unroll
    for (int i = 0; i < RROWS + 2; ++i) {
        hs[i].x = (hl[i]   + f[i].x + f[i].y) * valid[i];
        hs[i].y = (f[i].x + f[i].y + f[i].z) * valid[i];
        hs[i].z = (f[i].y + f[i].z + f[i].w) * valid[i];
        hs[i].w = (f[i].z + f[i].w + hr[i]) * valid[i];
    }

    // Vertical 3-sums + |x - mean|
    float acc = 0.f;
    const float inv9 = 1.f / 9.f;
    #pragma unroll
    for (int j = 0; j < RROWS; ++j) {
        const float sx = hs[j].x + hs[j + 1].x + hs[j + 2].x;
        const float sy = hs[j].y + hs[j + 1].y + hs[j + 2].y;
        const float sz = hs[j].z + hs[j + 1].z + hs[j + 2].z;
        const float sw = hs[j].w + hs[j + 1].w + hs[j + 2].w;
        acc += fabsf(f[j + 1].x - sx * inv9);
        acc += fabsf(f[j + 1].y - sy * inv9);
        acc += fabsf(f[j + 1].z - sz * inv9);
        acc += fabsf(f[j + 1].w - sw * inv9);
    }

    // Wave (64-lane) tree reduction, then block reduction.
    #pragma unroll
    for (int off = 32; off > 0; off >>= 1) acc += __shfl_down(acc, off, 64);

    __shared__ float smem[NTHREADS / 64];
    const int lane = threadIdx.x & 63;
    const int wid  = threadIdx.x >> 6;
    if (lane == 0) smem[wid] = acc;
    __syncthreads();
    if (threadIdx.x == 0) {
        float s = 0.f;
        #pragma unroll
        for (int i = 0; i < NTHREADS / 64; ++i) s += smem[i];
        partial[blockIdx.x] = s;
    }
}

__global__ __launch_bounds__(NTHREADS) void box_loss_final(
    const float* __restrict__ partial, float* __restrict__ out) {
    float acc = 0.f;
    for (int i = threadIdx.x; i < NBLOCKS; i += NTHREADS) acc += partial[i];
    #pragma unroll
    for (int off = 32; off > 0; off >>= 1) acc += __shfl_down(acc, off, 64);

    __shared__ float smem[NTHREADS / 64];
    const int lane = threadIdx.x & 63;
    const int wid  = threadIdx.x >> 6;
    if (lane == 0) smem[wid] = acc;
    __syncthreads();
    if (threadIdx.x == 0) {
        float s = 0.f;
        #pragma unroll
        for (int i = 0; i < NTHREADS / 64; ++i) s += smem[i];
        out[0] = s * (1.f / (float)TOTAL_ELEMS);
    }
}

extern "C" void kernel_launch(void* const* d_in, const int* in_sizes, int n_in,
                              void* d_out, int out_size, void* d_ws, size_t ws_size,
                              hipStream_t stream) {
    const float* x = (const float*)d_in[0];
    float* out = (float*)d_out;
    float* partial = (float*)d_ws;   // NBLOCKS floats = 38 KB

    box_loss_partial<<<NBLOCKS, NTHREADS, 0, stream>>>(x, partial);
    box_loss_final<<<1, NTHREADS, 0, stream>>>(partial, out);
}

// Round 3
// 61.673 us; speedup vs baseline: 2.9190x; 1.2188x over previous
//
#include <hip/hip_runtime.h>

// x shape (8, 19, 512, 1024) fp32
#define PH 512
#define PW 1024
#define NPLANES 152
#define TOTAL_ELEMS (152ll * 512 * 1024)   // 79,691,776
#define RROWS 16                           // output rows per thread
#define NTILES (PH / RROWS)                // 32
#define NBLOCKS (NPLANES * NTILES)         // 4864
#define NTHREADS 256
#define NXCD 8

__global__ __launch_bounds__(NTHREADS) void box_loss_partial(
    const float* __restrict__ x, float* __restrict__ partial) {
    // XCD-aware swizzle: each XCD gets a contiguous chunk of tiles so
    // adjacent tiles (sharing 2 halo rows) hit the same XCD's L2.
    // NBLOCKS % 8 == 0 -> bijective.
    const int bid = (int)blockIdx.x;
    const int swz = (bid & (NXCD - 1)) * (NBLOCKS / NXCD) + (bid >> 3);

    const int wv    = threadIdx.x;         // 0..255, float4 column
    const int tile  = swz & (NTILES - 1);
    const int plane = swz / NTILES;
    const int h0    = tile * RROWS;
    const int lane  = threadIdx.x & 63;

    const float* base = x + ((long long)plane << 19) + (wv << 2);

    // ---- Load 18 rows (16 + 2 halo), batched for MLP depth. ----
    float4 f[RROWS + 2];
    float  ed[RROWS + 2];   // seam value: lane0 -> row[-1], lane63 -> row[4]
    #pragma unroll
    for (int i = 0; i < RROWS + 2; ++i) {
        const int hh = h0 - 1 + i;
        const int hc = min(max(hh, 0), PH - 1);
        const float* row = base + (hc << 10);
        f[i] = *reinterpret_cast<const float4*>(row);
        float e = 0.f;
        if (lane == 0)       { if (wv > 0)   e = row[-1]; }
        else if (lane == 63) { if (wv < 255) e = row[4];  }
        ed[i] = e;
    }

    // ---- Horizontal 3-sum per row (shuffle halo), rolling vertical window. ----
    const float inv9 = 1.f / 9.f;
    float acc = 0.f;
    float4 h0v, h1v;

    #pragma unroll
    for (int i = 0; i < RROWS + 2; ++i) {
        const int hh = h0 - 1 + i;
        const float valid = (hh >= 0 && hh < PH) ? 1.f : 0.f;
        float hl = __shfl_up(f[i].w, 1, 64);
        if (lane == 0)  hl = ed[i];
        float hr = __shfl_down(f[i].x, 1, 64);
        if (lane == 63) hr = ed[i];
        float4 h2v;
        h2v.x = (hl     + f[i].x + f[i].y) * valid;
        h2v.y = (f[i].x + f[i].y + f[i].z) * valid;
        h2v.z = (f[i].y + f[i].z + f[i].w) * valid;
        h2v.w = (f[i].z + f[i].w + hr    ) * valid;

        if (i >= 2) {
            const float4 c = f[i - 1];
            acc += fabsf(c.x - (h0v.x + h1v.x + h2v.x) * inv9);
            acc += fabsf(c.y - (h0v.y + h1v.y + h2v.y) * inv9);
            acc += fabsf(c.z - (h0v.z + h1v.z + h2v.z) * inv9);
            acc += fabsf(c.w - (h0v.w + h1v.w + h2v.w) * inv9);
        }
        h0v = h1v;
        h1v = h2v;
    }

    // ---- Wave (64-lane) tree reduction, then block reduction. ----
    #pragma unroll
    for (int off = 32; off > 0; off >>= 1) acc += __shfl_down(acc, off, 64);

    __shared__ float smem[NTHREADS / 64];
    const int wid = threadIdx.x >> 6;
    if (lane == 0) smem[wid] = acc;
    __syncthreads();
    if (threadIdx.x == 0) {
        float s = 0.f;
        #pragma unroll
        for (int i = 0; i < NTHREADS / 64; ++i) s += smem[i];
        partial[blockIdx.x] = s;
    }
}

__global__ __launch_bounds__(NTHREADS) void box_loss_final(
    const float* __restrict__ partial, float* __restrict__ out) {
    float acc = 0.f;
    for (int i = threadIdx.x; i < NBLOCKS; i += NTHREADS) acc += partial[i];
    #pragma unroll
    for (int off = 32; off > 0; off >>= 1) acc += __shfl_down(acc, off, 64);

    __shared__ float smem[NTHREADS / 64];
    const int lane = threadIdx.x & 63;
    const int wid  = threadIdx.x >> 6;
    if (lane == 0) smem[wid] = acc;
    __syncthreads();
    if (threadIdx.x == 0) {
        float s = 0.f;
        #pragma unroll
        for (int i = 0; i < NTHREADS / 64; ++i) s += smem[i];
        out[0] = s * (1.f / (float)TOTAL_ELEMS);
    }
}

extern "C" void kernel_launch(void* const* d_in, const int* in_sizes, int n_in,
                              void* d_out, int out_size, void* d_ws, size_t ws_size,
                              hipStream_t stream) {
    const float* x = (const float*)d_in[0];
    float* out = (float*)d_out;
    float* partial = (float*)d_ws;   // NBLOCKS floats = 19 KB

    box_loss_partial<<<NBLOCKS, NTHREADS, 0, stream>>>(x, partial);
    box_loss_final<<<1, NTHREADS, 0, stream>>>(partial, out);
}

// Round 4
// 59.403 us; speedup vs baseline: 3.0306x; 1.0382x over previous
//
#include <hip/hip_runtime.h>

// x shape (8, 19, 512, 1024) fp32
#define PH 512
#define PW 1024
#define NPLANES 152
#define TOTAL_ELEMS (152ll * 512 * 1024)   // 79,691,776
#define RROWS 16                           // output rows per thread
#define NTILES (PH / RROWS)                // 32
#define NBLOCKS (NPLANES * NTILES)         // 4864
#define NTHREADS 256
#define NXCD 8

__global__ __launch_bounds__(NTHREADS) void box_loss_partial(
    const float* __restrict__ x, float* __restrict__ partial) {
    // XCD-aware swizzle: adjacent tiles (sharing 2 halo rows) stay on the
    // same XCD's L2. NBLOCKS % 8 == 0 -> bijective.
    const int bid = (int)blockIdx.x;
    const int swz = (bid & (NXCD - 1)) * (NBLOCKS / NXCD) + (bid >> 3);

    const int wv    = threadIdx.x;         // 0..255, float4 column
    const int tile  = swz & (NTILES - 1);
    const int plane = swz / NTILES;
    const int h0    = tile * RROWS;
    const int lane  = threadIdx.x & 63;
    const int wid   = threadIdx.x >> 6;    // wave id 0..3

    const float* base = x + ((long long)plane << 19) + (wv << 2);

    // Inter-wave seam exchange buffers (block spans the full row, so all
    // seams are internal): eL = f.x of lane0 per wave, eR = f.w of lane63.
    __shared__ float eL[RROWS + 2][4];
    __shared__ float eR[RROWS + 2][4];

    // ---- Load 18 rows (16 + 2 halo), batched for MLP depth. ----
    float4 f[RROWS + 2];
    #pragma unroll
    for (int i = 0; i < RROWS + 2; ++i) {
        const int hh = h0 - 1 + i;
        const int hc = min(max(hh, 0), PH - 1);
        f[i] = *reinterpret_cast<const float4*>(base + (hc << 10));
    }
    #pragma unroll
    for (int i = 0; i < RROWS + 2; ++i) {
        if (lane == 0)  eL[i][wid] = f[i].x;
        if (lane == 63) eR[i][wid] = f[i].w;
    }
    __syncthreads();

    // ---- Horizontal 3-sum per row (shuffle + LDS seams), rolling window. ----
    const float inv9 = 1.f / 9.f;
    float acc = 0.f;
    float4 h0v, h1v;

    #pragma unroll
    for (int i = 0; i < RROWS + 2; ++i) {
        const int hh = h0 - 1 + i;
        const float valid = (hh >= 0 && hh < PH) ? 1.f : 0.f;
        float hl = __shfl_up(f[i].w, 1, 64);
        if (lane == 0)  hl = (wid > 0) ? eR[i][wid - 1] : 0.f;   // image left pad
        float hr = __shfl_down(f[i].x, 1, 64);
        if (lane == 63) hr = (wid < 3) ? eL[i][wid + 1] : 0.f;   // image right pad
        float4 h2v;
        h2v.x = (hl     + f[i].x + f[i].y) * valid;
        h2v.y = (f[i].x + f[i].y + f[i].z) * valid;
        h2v.z = (f[i].y + f[i].z + f[i].w) * valid;
        h2v.w = (f[i].z + f[i].w + hr    ) * valid;

        if (i >= 2) {
            const float4 c = f[i - 1];
            acc += fabsf(c.x - (h0v.x + h1v.x + h2v.x) * inv9);
            acc += fabsf(c.y - (h0v.y + h1v.y + h2v.y) * inv9);
            acc += fabsf(c.z - (h0v.z + h1v.z + h2v.z) * inv9);
            acc += fabsf(c.w - (h0v.w + h1v.w + h2v.w) * inv9);
        }
        h0v = h1v;
        h1v = h2v;
    }

    // ---- Wave (64-lane) tree reduction, then block reduction. ----
    #pragma unroll
    for (int off = 32; off > 0; off >>= 1) acc += __shfl_down(acc, off, 64);

    __shared__ float smem[NTHREADS / 64];
    if (lane == 0) smem[wid] = acc;
    __syncthreads();
    if (threadIdx.x == 0) {
        float s = 0.f;
        #pragma unroll
        for (int i = 0; i < NTHREADS / 64; ++i) s += smem[i];
        partial[blockIdx.x] = s;
    }
}

__global__ __launch_bounds__(NTHREADS) void box_loss_final(
    const float* __restrict__ partial, float* __restrict__ out) {
    float acc = 0.f;
    for (int i = threadIdx.x; i < NBLOCKS; i += NTHREADS) acc += partial[i];
    #pragma unroll
    for (int off = 32; off > 0; off >>= 1) acc += __shfl_down(acc, off, 64);

    __shared__ float smem[NTHREADS / 64];
    const int lane = threadIdx.x & 63;
    const int wid  = threadIdx.x >> 6;
    if (lane == 0) smem[wid] = acc;
    __syncthreads();
    if (threadIdx.x == 0) {
        float s = 0.f;
        #pragma unroll
        for (int i = 0; i < NTHREADS / 64; ++i) s += smem[i];
        out[0] = s * (1.f / (float)TOTAL_ELEMS);
    }
}

extern "C" void kernel_launch(void* const* d_in, const int* in_sizes, int n_in,
                              void* d_out, int out_size, void* d_ws, size_t ws_size,
                              hipStream_t stream) {
    const float* x = (const float*)d_in[0];
    float* out = (float*)d_out;
    float* partial = (float*)d_ws;   // NBLOCKS floats = 19 KB

    box_loss_partial<<<NBLOCKS, NTHREADS, 0, stream>>>(x, partial);
    box_loss_final<<<1, NTHREADS, 0, stream>>>(partial, out);
}